// Round 2
// baseline (2432.868 us; speedup 1.0000x reference)
//
#include <hip/hip_runtime.h>
#include <math.h>

// Problem constants (from reference setup_inputs): B=8,T=2048,D=512,N=4096
static constexpr int D    = 512;
static constexpr int NPOS = 4096;
static constexpr int M    = 16384;
static constexpr float MIN_SCALE = 0.05f;

#define MT 32      // M rows per block
#define NT 256     // N tile
#define KC 32      // K chunk
#define VJ 16      // V rows per LDS chunk

// ---------------------------------------------------------------------------
// Precompute: pnorm[n] = ||positions[n]||^2 ; neg_invt[n] = -1/((|t|+0.1)*scale)
// ws layout: floats [0..NPOS) = pnorm, [NPOS..2*NPOS) = neg_invt
// ---------------------------------------------------------------------------
__global__ __launch_bounds__(256) void precompute_kernel(
    const float* __restrict__ positions, const float* __restrict__ temperature,
    const float* __restrict__ frozen_scale, const int* __restrict__ frozen,
    float* __restrict__ ws)
{
    const int wv   = threadIdx.x >> 6;
    const int lane = threadIdx.x & 63;
    const int n    = blockIdx.x * 4 + wv;
    const float* row = positions + (size_t)n * D;
    float s = 0.f;
    #pragma unroll
    for (int q = 0; q < D; q += 64) { float v = row[q + lane]; s += v * v; }
    #pragma unroll
    for (int off = 32; off > 0; off >>= 1) s += __shfl_down(s, off, 64);
    if (lane == 0) {
        ws[n] = s;
        float es = (frozen[n] != 0) ? frozen_scale[n] : MIN_SCALE;  // int32 per harness contract
        float et = (fabsf(temperature[n]) + 0.1f) * es;
        ws[NPOS + n] = -1.0f / et;
    }
}

// ---------------------------------------------------------------------------
// Fused kernel: per block of 32 rows, iterate N in tiles of 256:
//   S = x.posT (fp32, LDS-staged, reg-blocked 8r x 4c)
//   w = exp(-sqrt(max(xn+pn-2S,0))/temp) -> LDS wT[32][260], den accumulated
//   acc += w @ V   (V streamed in 16-row LDS chunks, reg-blocked 8r x 8c)
// Final: out = acc / (den + 1e-8), den reduced by wave shuffle.
// ---------------------------------------------------------------------------
__global__ __launch_bounds__(256, 2) void tidal_kernel(
    const float* __restrict__ x, const float* __restrict__ positions,
    const float* __restrict__ values, const float* __restrict__ ws,
    float* __restrict__ out)
{
    __shared__ __attribute__((aligned(16))) float buf[KC * 260];  // posT[KC][260]  U  V[VJ][512]
    __shared__ __attribute__((aligned(16))) float wT[MT][260];
    __shared__ __attribute__((aligned(16))) float xT[KC][MT];
    __shared__ float xn[MT];

    const int tid  = threadIdx.x;
    const int lane = tid & 63;   // cg: column group
    const int wv   = tid >> 6;   // rg: row group (one wave per 8 rows)
    const int m0   = blockIdx.x * MT;

    // x row norms (wave wv handles rows wv*8..wv*8+7)
    #pragma unroll
    for (int rr = 0; rr < 8; ++rr) {
        const int r = wv * 8 + rr;
        const float* xr = x + (size_t)(m0 + r) * D;
        float s = 0.f;
        #pragma unroll
        for (int q = 0; q < D; q += 64) { float v = xr[q + lane]; s += v * v; }
        #pragma unroll
        for (int off = 32; off > 0; off >>= 1) s += __shfl_down(s, off, 64);
        if (lane == 0) xn[r] = s;
    }

    float4 acc[8][2];
    #pragma unroll
    for (int a = 0; a < 8; ++a) { acc[a][0] = make_float4(0,0,0,0); acc[a][1] = make_float4(0,0,0,0); }
    float den[8];
    #pragma unroll
    for (int a = 0; a < 8; ++a) den[a] = 0.f;

    for (int tile = 0; tile < NPOS / NT; ++tile) {
        const int n0 = tile * NT;

        // ---------------- GEMM1: S[32][256] ----------------
        float s[8][4];
        #pragma unroll
        for (int a = 0; a < 8; ++a)
            #pragma unroll
            for (int b = 0; b < 4; ++b) s[a][b] = 0.f;

        for (int k0 = 0; k0 < D; k0 += KC) {
            __syncthreads();   // buf/xT free (prev compute done)
            {   // stage xT[KC][32] (transposed x chunk)
                const int r  = tid >> 3;
                const int kl = (tid & 7) * 4;
                const float4 xv = *(const float4*)(x + (size_t)(m0 + r) * D + k0 + kl);
                xT[kl + 0][r] = xv.x; xT[kl + 1][r] = xv.y;
                xT[kl + 2][r] = xv.z; xT[kl + 3][r] = xv.w;
            }
            {   // stage posT[KC][260] into buf (transposed pos chunk)
                const int kl = (tid & 7) * 4;
                #pragma unroll
                for (int p = 0; p < 8; ++p) {
                    const int nl = (tid >> 3) + 32 * p;
                    const float4 pv = *(const float4*)(positions + (size_t)(n0 + nl) * D + k0 + kl);
                    buf[(kl + 0) * 260 + nl] = pv.x;
                    buf[(kl + 1) * 260 + nl] = pv.y;
                    buf[(kl + 2) * 260 + nl] = pv.z;
                    buf[(kl + 3) * 260 + nl] = pv.w;
                }
            }
            __syncthreads();
            #pragma unroll
            for (int k = 0; k < KC; ++k) {
                const float4 xa = *(const float4*)&xT[k][wv * 8 + 0];   // broadcast
                const float4 xb = *(const float4*)&xT[k][wv * 8 + 4];   // broadcast
                const float4 pv = *(const float4*)&buf[k * 260 + lane * 4];
                const float xr8[8] = {xa.x, xa.y, xa.z, xa.w, xb.x, xb.y, xb.z, xb.w};
                const float pc4[4] = {pv.x, pv.y, pv.z, pv.w};
                #pragma unroll
                for (int a = 0; a < 8; ++a)
                    #pragma unroll
                    for (int b = 0; b < 4; ++b)
                        s[a][b] = fmaf(xr8[a], pc4[b], s[a][b]);
            }
        }

        // ---------------- epilogue: w = exp(-dist/temp) -> wT, den ----------------
        {
            const float4 pn = *(const float4*)(ws + n0 + lane * 4);
            const float4 it = *(const float4*)(ws + NPOS + n0 + lane * 4);  // already -1/temp
            #pragma unroll
            for (int a = 0; a < 8; ++a) {
                const float xnr = xn[wv * 8 + a];
                float4 wvv;
                wvv.x = __expf(sqrtf(fmaxf(xnr + pn.x - 2.f * s[a][0], 0.f)) * it.x);
                wvv.y = __expf(sqrtf(fmaxf(xnr + pn.y - 2.f * s[a][1], 0.f)) * it.y);
                wvv.z = __expf(sqrtf(fmaxf(xnr + pn.z - 2.f * s[a][2], 0.f)) * it.z);
                wvv.w = __expf(sqrtf(fmaxf(xnr + pn.w - 2.f * s[a][3], 0.f)) * it.w);
                den[a] += (wvv.x + wvv.y) + (wvv.z + wvv.w);
                *(float4*)&wT[wv * 8 + a][lane * 4] = wvv;   // contiguous b128 across lanes
            }
        }

        // ---------------- GEMM2: acc += wT(,tile) @ V ----------------
        for (int jc = 0; jc < NT / VJ; ++jc) {
            __syncthreads();   // buf free (also orders wT write -> read on jc=0)
            {   // stage V chunk [VJ][512] into buf
                const int jl = tid >> 4;
                const int cb = (tid & 15) * 4;
                #pragma unroll
                for (int p = 0; p < 8; ++p) {
                    const int c = cb + 64 * p;
                    const float4 vv = *(const float4*)(values + (size_t)(n0 + jc * VJ + jl) * D + c);
                    *(float4*)&buf[jl * 512 + c] = vv;
                }
            }
            __syncthreads();
            #pragma unroll
            for (int j = 0; j < VJ; ++j) {
                const float4 va = *(const float4*)&buf[j * 512 + lane * 4];
                const float4 vb = *(const float4*)&buf[j * 512 + 256 + lane * 4];
                float wj[8];
                #pragma unroll
                for (int a = 0; a < 8; ++a) wj[a] = wT[wv * 8 + a][jc * VJ + j];  // broadcast
                #pragma unroll
                for (int a = 0; a < 8; ++a) {
                    acc[a][0].x = fmaf(wj[a], va.x, acc[a][0].x);
                    acc[a][0].y = fmaf(wj[a], va.y, acc[a][0].y);
                    acc[a][0].z = fmaf(wj[a], va.z, acc[a][0].z);
                    acc[a][0].w = fmaf(wj[a], va.w, acc[a][0].w);
                    acc[a][1].x = fmaf(wj[a], vb.x, acc[a][1].x);
                    acc[a][1].y = fmaf(wj[a], vb.y, acc[a][1].y);
                    acc[a][1].z = fmaf(wj[a], vb.z, acc[a][1].z);
                    acc[a][1].w = fmaf(wj[a], vb.w, acc[a][1].w);
                }
            }
        }
    }

    // ---------------- normalize + store ----------------
    #pragma unroll
    for (int a = 0; a < 8; ++a) {
        float dsum = den[a];
        #pragma unroll
        for (int off = 32; off > 0; off >>= 1) dsum += __shfl_down(dsum, off, 64);
        dsum = __shfl(dsum, 0, 64);
        const float sc = 1.0f / (dsum + 1e-8f);
        const int row = m0 + wv * 8 + a;
        float4 o0 = acc[a][0], o1 = acc[a][1];
        o0.x *= sc; o0.y *= sc; o0.z *= sc; o0.w *= sc;
        o1.x *= sc; o1.y *= sc; o1.z *= sc; o1.w *= sc;
        *(float4*)(out + (size_t)row * D + lane * 4)       = o0;
        *(float4*)(out + (size_t)row * D + 256 + lane * 4) = o1;
    }
}

extern "C" void kernel_launch(void* const* d_in, const int* in_sizes, int n_in,
                              void* d_out, int out_size, void* d_ws, size_t ws_size,
                              hipStream_t stream) {
    const float* xp  = (const float*)d_in[0];
    const float* pos = (const float*)d_in[1];
    const float* val = (const float*)d_in[2];
    const float* tmp = (const float*)d_in[3];
    const float* fsc = (const float*)d_in[4];
    const int*   frz = (const int*)d_in[5];
    float* outp = (float*)d_out;
    float* ws   = (float*)d_ws;

    precompute_kernel<<<NPOS / 4, 256, 0, stream>>>(pos, tmp, fsc, frz, ws);
    tidal_kernel<<<M / MT, 256, 0, stream>>>(xp, pos, val, ws, outp);
}

// Round 3
// 765.104 us; speedup vs baseline: 3.1798x; 3.1798x over previous
//
#include <hip/hip_runtime.h>
#include <math.h>

// B=8,T=2048,D=512,N=4096
static constexpr int D    = 512;
static constexpr int NPOS = 4096;
static constexpr int M    = 16384;
static constexpr float MIN_SCALE = 0.05f;

typedef __attribute__((ext_vector_type(8))) short short8_t;           // bf16x8 MFMA frag (4 VGPR)
typedef __attribute__((ext_vector_type(4))) float f32x4_t;            // MFMA acc
typedef __attribute__((ext_vector_type(8))) unsigned short ushort8_t; // 16B LDS store

__device__ __forceinline__ unsigned short f2bf(float f) {
    unsigned u = __float_as_uint(f);
    unsigned r = (u + 0x7FFFu + ((u >> 16) & 1u)) >> 16;  // RN-even
    return (unsigned short)r;
}
__device__ __forceinline__ float bf2f(unsigned short h) {
    return __uint_as_float(((unsigned)h) << 16);
}

// ---------------------------------------------------------------------------
// ws: [0..NPOS) pnorm, [NPOS..2*NPOS) -1/((|t|+0.1)*scale)
// ---------------------------------------------------------------------------
__global__ __launch_bounds__(256) void precompute_kernel(
    const float* __restrict__ positions, const float* __restrict__ temperature,
    const float* __restrict__ frozen_scale, const int* __restrict__ frozen,
    float* __restrict__ ws)
{
    const int wv   = threadIdx.x >> 6;
    const int lane = threadIdx.x & 63;
    const int n    = blockIdx.x * 4 + wv;
    const float* row = positions + (size_t)n * D;
    float s = 0.f;
    #pragma unroll
    for (int q = 0; q < D; q += 64) { float v = row[q + lane]; s += v * v; }
    #pragma unroll
    for (int off = 32; off > 0; off >>= 1) s += __shfl_down(s, off, 64);
    if (lane == 0) {
        ws[n] = s;
        float es = (frozen[n] != 0) ? frozen_scale[n] : MIN_SCALE;
        float et = (fabsf(temperature[n]) + 0.1f) * es;
        ws[NPOS + n] = -1.0f / et;
    }
}

// ---------------------------------------------------------------------------
// Fused MFMA kernel. Per block: 64 rows. N-tiles of 256.
//   GEMM1: S = (x_hi + x_lo) @ p_bf^T  (2 bf16 MFMA passes, fp32 acc)
//   w = exp(-sqrt(max(xn+pn-2S,0))/temp) -> WT bf16, den += row-sums (from bf16 w)
//   GEMM2: O += WT @ V_bf (V staged transposed per 64-chunk)
// Final: out = O / (den + 1e-8)
// ---------------------------------------------------------------------------
#define SMEM_BYTES (73728 + 33792 + 512)

__global__ __launch_bounds__(512) void tidal_mfma(
    const float* __restrict__ x, const float* __restrict__ pos,
    const float* __restrict__ val, const float* __restrict__ ws,
    float* __restrict__ out)
{
    __shared__ __attribute__((aligned(16))) unsigned char smem[SMEM_BYTES];
    unsigned short* XH = (unsigned short*)smem;            // [64][72] bf16 x-hi chunk
    unsigned short* XL = XH + 64 * 72;                     // [64][72] bf16 x-lo chunk
    unsigned short* PB = XL + 64 * 72;                     // [256][72] bf16 p chunk
    unsigned short* VT = (unsigned short*)smem;            // [512][72] bf16 V^T chunk (aliases XH/XL/PB)
    unsigned short* WT = (unsigned short*)(smem + 73728);  // [64][264] bf16 weights
    float* xn_s  = (float*)(smem + 73728 + 33792);         // [64]
    float* den_s = xn_s + 64;                              // [64]

    const int tid  = threadIdx.x;
    const int lane = tid & 63;
    const int wave = tid >> 6;       // 0..7
    const int q    = lane >> 4;      // quad 0..3
    const int l15  = lane & 15;
    const int wr   = wave & 1;       // row half: rows 32*wr..+32
    const int wc   = wave >> 1;      // col quarter 0..3
    const int m0   = blockIdx.x * 64;

    // x row norms (fp32 exact): wave handles rows wave*8..+8
    #pragma unroll
    for (int rr = 0; rr < 8; ++rr) {
        const int r = wave * 8 + rr;
        const float* xr = x + (size_t)(m0 + r) * D;
        float s = 0.f;
        #pragma unroll
        for (int c = 0; c < 8; ++c) { float v = xr[c * 64 + lane]; s += v * v; }
        #pragma unroll
        for (int off = 32; off > 0; off >>= 1) s += __shfl_down(s, off, 64);
        if (lane == 0) xn_s[r] = s;
    }
    if (tid < 64) den_s[tid] = 0.f;

    f32x4_t O[2][8];
    #pragma unroll
    for (int i = 0; i < 2; ++i)
        #pragma unroll
        for (int jj = 0; jj < 8; ++jj) O[i][jj] = (f32x4_t)0.f;

    for (int tile = 0; tile < NPOS / 256; ++tile) {
        const int n0 = tile * 256;

        // ================= GEMM1: S[64][256] =================
        f32x4_t S[2][4];
        #pragma unroll
        for (int i = 0; i < 2; ++i)
            #pragma unroll
            for (int j = 0; j < 4; ++j) S[i][j] = (f32x4_t)0.f;

        for (int kc = 0; kc < 8; ++kc) {
            const int k0 = kc * 64;
            __syncthreads();
            {   // stage x hi/lo: row=tid>>3, k=(tid&7)*8..+8
                const int r = tid >> 3, kb = (tid & 7) * 8;
                const float* src = x + (size_t)(m0 + r) * D + k0 + kb;
                const float4 a0 = *(const float4*)src;
                const float4 a1 = *(const float4*)(src + 4);
                const float vv[8] = {a0.x, a0.y, a0.z, a0.w, a1.x, a1.y, a1.z, a1.w};
                ushort8_t hv, lv;
                #pragma unroll
                for (int c = 0; c < 8; ++c) {
                    const unsigned short h = f2bf(vv[c]);
                    hv[c] = h;
                    lv[c] = f2bf(vv[c] - bf2f(h));
                }
                *(ushort8_t*)&XH[r * 72 + kb] = hv;
                *(ushort8_t*)&XL[r * 72 + kb] = lv;
            }
            {   // stage p (single bf16): row=tid>>1, k=(tid&1)*32..+32
                const int r = tid >> 1, kb = (tid & 1) * 32;
                const float* src = pos + (size_t)(n0 + r) * D + k0 + kb;
                #pragma unroll
                for (int g = 0; g < 2; ++g) {
                    const float4 b0 = *(const float4*)(src + g * 16);
                    const float4 b1 = *(const float4*)(src + g * 16 + 4);
                    const float4 b2 = *(const float4*)(src + g * 16 + 8);
                    const float4 b3 = *(const float4*)(src + g * 16 + 12);
                    const float vv[16] = {b0.x,b0.y,b0.z,b0.w, b1.x,b1.y,b1.z,b1.w,
                                          b2.x,b2.y,b2.z,b2.w, b3.x,b3.y,b3.z,b3.w};
                    ushort8_t p0, p1;
                    #pragma unroll
                    for (int c = 0; c < 8; ++c) { p0[c] = f2bf(vv[c]); p1[c] = f2bf(vv[8 + c]); }
                    *(ushort8_t*)&PB[r * 72 + kb + g * 16]     = p0;
                    *(ushort8_t*)&PB[r * 72 + kb + g * 16 + 8] = p1;
                }
            }
            __syncthreads();
            #pragma unroll
            for (int ks = 0; ks < 2; ++ks) {
                const int ko = ks * 32 + q * 8;
                short8_t ah[2], al[2], bh[4];
                #pragma unroll
                for (int i = 0; i < 2; ++i) {
                    ah[i] = *(short8_t*)&XH[(wr * 32 + i * 16 + l15) * 72 + ko];
                    al[i] = *(short8_t*)&XL[(wr * 32 + i * 16 + l15) * 72 + ko];
                }
                #pragma unroll
                for (int j = 0; j < 4; ++j)
                    bh[j] = *(short8_t*)&PB[(wc * 64 + j * 16 + l15) * 72 + ko];
                #pragma unroll
                for (int j = 0; j < 4; ++j)
                    #pragma unroll
                    for (int i = 0; i < 2; ++i) {
                        S[i][j] = __builtin_amdgcn_mfma_f32_16x16x32_bf16(ah[i], bh[j], S[i][j], 0, 0, 0);
                        S[i][j] = __builtin_amdgcn_mfma_f32_16x16x32_bf16(al[i], bh[j], S[i][j], 0, 0, 0);
                    }
            }
        }

        // ====== epilogue: w = exp(-dist/temp), WT bf16, den ======
        #pragma unroll
        for (int j = 0; j < 4; ++j) {
            const int cg   = n0 + wc * 64 + j * 16 + l15;
            const float pn  = ws[cg];
            const float nit = ws[NPOS + cg];   // already -1/temp
            #pragma unroll
            for (int i = 0; i < 2; ++i) {
                #pragma unroll
                for (int r = 0; r < 4; ++r) {
                    const int row = wr * 32 + i * 16 + q * 4 + r;
                    const float d2 = xn_s[row] + pn - 2.f * S[i][j][r];
                    const float w  = __expf(sqrtf(fmaxf(d2, 0.f)) * nit);
                    WT[row * 264 + wc * 64 + j * 16 + l15] = f2bf(w);
                }
            }
        }
        __syncthreads();
        {   // den += row sums of bf16 w (consistent with GEMM2 numerator)
            const int row = tid >> 3, cb = (tid & 7) * 32;
            float s = 0.f;
            #pragma unroll
            for (int g = 0; g < 4; ++g) {
                const ushort8_t wv = *(ushort8_t*)&WT[row * 264 + cb + g * 8];
                #pragma unroll
                for (int c = 0; c < 8; ++c) s += bf2f(wv[c]);
            }
            s += __shfl_xor(s, 1, 64);
            s += __shfl_xor(s, 2, 64);
            s += __shfl_xor(s, 4, 64);
            if ((tid & 7) == 0) den_s[row] += s;
        }

        // ================= GEMM2: O += WT @ V =================
        for (int nc = 0; nc < 4; ++nc) {
            const int nb = nc * 64;
            __syncthreads();
            {   // stage V transposed: VT[d][nl], nl=tid>>3 (0..63), d=(tid&7)*4 + 32m
                const int nl = tid >> 3, db = (tid & 7) * 4;
                const float* src = val + (size_t)(n0 + nb + nl) * D;
                #pragma unroll
                for (int mm = 0; mm < 16; ++mm) {
                    const int d = db + mm * 32;
                    const float4 v4 = *(const float4*)(src + d);
                    VT[(d + 0) * 72 + nl] = f2bf(v4.x);
                    VT[(d + 1) * 72 + nl] = f2bf(v4.y);
                    VT[(d + 2) * 72 + nl] = f2bf(v4.z);
                    VT[(d + 3) * 72 + nl] = f2bf(v4.w);
                }
            }
            __syncthreads();
            #pragma unroll
            for (int ks = 0; ks < 2; ++ks) {
                const int ko = ks * 32 + q * 8;
                short8_t aw[2], bv[8];
                #pragma unroll
                for (int i = 0; i < 2; ++i)
                    aw[i] = *(short8_t*)&WT[(wr * 32 + i * 16 + l15) * 264 + nb + ko];
                #pragma unroll
                for (int jj = 0; jj < 8; ++jj)
                    bv[jj] = *(short8_t*)&VT[(wc * 128 + jj * 16 + l15) * 72 + ko];
                #pragma unroll
                for (int jj = 0; jj < 8; ++jj)
                    #pragma unroll
                    for (int i = 0; i < 2; ++i)
                        O[i][jj] = __builtin_amdgcn_mfma_f32_16x16x32_bf16(aw[i], bv[jj], O[i][jj], 0, 0, 0);
            }
        }
    }

    // ================= normalize + store =================
    #pragma unroll
    for (int i = 0; i < 2; ++i) {
        #pragma unroll
        for (int r = 0; r < 4; ++r) {
            const int row = wr * 32 + i * 16 + q * 4 + r;
            const float inv = 1.f / (den_s[row] + 1e-8f);
            float* orow = out + (size_t)(m0 + row) * D + wc * 128 + l15;
            #pragma unroll
            for (int jj = 0; jj < 8; ++jj)
                orow[jj * 16] = O[i][jj][r] * inv;
        }
    }
}

extern "C" void kernel_launch(void* const* d_in, const int* in_sizes, int n_in,
                              void* d_out, int out_size, void* d_ws, size_t ws_size,
                              hipStream_t stream) {
    const float* xp  = (const float*)d_in[0];
    const float* pos = (const float*)d_in[1];
    const float* val = (const float*)d_in[2];
    const float* tmp = (const float*)d_in[3];
    const float* fsc = (const float*)d_in[4];
    const int*   frz = (const int*)d_in[5];
    float* outp = (float*)d_out;
    float* ws   = (float*)d_ws;

    precompute_kernel<<<NPOS / 4, 256, 0, stream>>>(pos, tmp, fsc, frz, ws);
    tidal_mfma<<<M / 64, 512, 0, stream>>>(xp, pos, val, ws, outp);
}

// Round 5
// 611.025 us; speedup vs baseline: 3.9816x; 1.2522x over previous
//
#include <hip/hip_runtime.h>
#include <math.h>

// B=8,T=2048,D=512,N=4096
static constexpr int D    = 512;
static constexpr int NPOS = 4096;
static constexpr int M    = 16384;
static constexpr float MIN_SCALE = 0.05f;

typedef unsigned short u16;
typedef __attribute__((ext_vector_type(8))) short short8_t;            // bf16x8 MFMA frag
typedef __attribute__((ext_vector_type(4))) float f32x4_t;             // MFMA acc
typedef __attribute__((ext_vector_type(8))) unsigned short ushort8_t;  // 16B store

__device__ __forceinline__ u16 f2bf(float f) {
    unsigned u = __float_as_uint(f);
    unsigned r = (u + 0x7FFFu + ((u >> 16) & 1u)) >> 16;  // RN-even
    return (u16)r;
}
__device__ __forceinline__ float bf2f(u16 h) {
    return __uint_as_float(((unsigned)h) << 16);
}
// async global->LDS, 16B per lane; lds base must be wave-uniform (HW adds lane*16)
__device__ __forceinline__ void async16(void* lds, const void* gp) {
    __builtin_amdgcn_global_load_lds(
        (const __attribute__((address_space(1))) unsigned int*)gp,
        (__attribute__((address_space(3))) unsigned int*)lds, 16, 0, 0);
}

// ws layout (bytes): [0) pnorm f32[4096]  [16384) neg_invt f32[4096]
//                    [32768) PB_g bf16 [4096][512] swizzled
//                    [32768+4194304) VT_g bf16 [512][4096] transposed+swizzled
// swizzle: within each 64-elem chunk of the contraction row, 16B group g is
// stored at slot g ^ (row & 7).

// ---------------------------------------------------------------------------
__global__ __launch_bounds__(256) void pn_kernel(
    const float* __restrict__ positions, const float* __restrict__ temperature,
    const float* __restrict__ frozen_scale, const int* __restrict__ frozen,
    float* __restrict__ ws)
{
    const int wv   = threadIdx.x >> 6;
    const int lane = threadIdx.x & 63;
    const int n    = blockIdx.x * 4 + wv;
    const float* row = positions + (size_t)n * D;
    float s = 0.f;
    #pragma unroll
    for (int q = 0; q < D; q += 64) { float v = row[q + lane]; s += v * v; }
    #pragma unroll
    for (int off = 32; off > 0; off >>= 1) s += __shfl_down(s, off, 64);
    if (lane == 0) {
        ws[n] = s;
        float es = (frozen[n] != 0) ? frozen_scale[n] : MIN_SCALE;
        float et = (fabsf(temperature[n]) + 0.1f) * es;
        ws[NPOS + n] = -1.0f / et;
    }
}

// p -> bf16, row-major [n][512], 16B groups swizzled within 64-k chunks
__global__ __launch_bounds__(256) void pb_pre(const float* __restrict__ pos,
                                              u16* __restrict__ pb) {
    const int gid = blockIdx.x * 256 + threadIdx.x;  // 4096*64
    const int n = gid >> 6, gf = gid & 63;
    const float* src = pos + (size_t)n * D + gf * 8;
    const float4 a = *(const float4*)src;
    const float4 b = *(const float4*)(src + 4);
    ushort8_t v;
    v[0]=f2bf(a.x); v[1]=f2bf(a.y); v[2]=f2bf(a.z); v[3]=f2bf(a.w);
    v[4]=f2bf(b.x); v[5]=f2bf(b.y); v[6]=f2bf(b.z); v[7]=f2bf(b.w);
    const int kc = gf >> 3, g = gf & 7;
    *(ushort8_t*)&pb[(size_t)n * D + kc * 64 + ((g ^ (n & 7)) * 8)] = v;
}

// V -> bf16 transposed [d][n=4096], 16B n-groups swizzled within 64-n chunks
__global__ __launch_bounds__(256) void vt_pre(const float* __restrict__ val,
                                              u16* __restrict__ vt) {
    __shared__ __attribute__((aligned(16))) float tile[64 * 68];
    const int n0 = blockIdx.x * 64, d0 = blockIdx.y * 64;
    const int t = threadIdx.x;
    {
        const int nr = t >> 2, c0 = (t & 3) * 16;
        const float* src = val + (size_t)(n0 + nr) * D + d0 + c0;
        #pragma unroll
        for (int i = 0; i < 4; ++i)
            *(float4*)&tile[nr * 68 + c0 + i * 4] = *(const float4*)(src + i * 4);
    }
    __syncthreads();
    {
        const int dr = t >> 2, gs = t & 3;
        #pragma unroll
        for (int gg = 0; gg < 2; ++gg) {
            const int g = gs * 2 + gg;
            ushort8_t v;
            #pragma unroll
            for (int e = 0; e < 8; ++e) v[e] = f2bf(tile[(g * 8 + e) * 68 + dr]);
            *(ushort8_t*)&vt[(size_t)(d0 + dr) * NPOS + n0 + ((g ^ (dr & 7)) * 8)] = v;
        }
    }
}

// ---------------------------------------------------------------------------
// Main fused kernel: 512 blocks x 512 threads, 32 m-rows/block, N-tile 256.
// GEMM1: S^T = p_bf @ x^T (hi+lo), A=PB(LDS, async-staged), B=x(global->reg cvt)
// epilogue: w=exp(-d/t) -> WT bf16 (swizzled b32 writes), den in regs
// GEMM2: O += WT @ V via VT chunks (async-staged, double-buffered)
// LDS: PBbuf 2x32KB (stage dbuf, VT overlays) + WT 16KB = 80KB -> 2 blocks/CU
// ---------------------------------------------------------------------------
__global__ __launch_bounds__(512, 4) void tidal_mfma(
    const float* __restrict__ x, const float* __restrict__ ws_f,
    const u16* __restrict__ pb_g, const u16* __restrict__ vt_g,
    float* __restrict__ out)
{
    __shared__ __attribute__((aligned(16))) u16 PBbuf[2][256 * 64];
    __shared__ __attribute__((aligned(16))) u16 WT[32 * 256];

    const float* pn_arr = ws_f;
    const float* it_arr = ws_f + NPOS;

    const int tid  = threadIdx.x;
    const int lane = tid & 63;
    const int wave = tid >> 6;       // 0..7
    const int q    = lane >> 4;
    const int l15  = lane & 15;
    const int wr   = wave & 1;       // m-half (16 rows)
    const int wc   = wave >> 1;      // n-quarter / d-group
    const int m0   = blockIdx.x * 32;
    const int swz  = (l15 & 7);      // row&7 for both WT(m) and PB/VT frag rows

    // stage PB chunk kc into buffer b (4 x 1KB segments per wave)
    auto stage_pb = [&](int kc_, int b_) {
        #pragma unroll
        for (int s_ = 0; s_ < 4; ++s_) {
            const int seg = wave * 4 + s_;
            const int nrel = seg * 8 + (lane >> 3);
            const u16* gp = pb_g + (size_t)(blockIdx.y * 0) /*noop*/
                            + (size_t)(s_ * 0)
                            + 0;
            (void)gp;
            const u16* gp2 = pb_g;
            (void)gp2;
            // real address (kept simple for the compiler):
            const u16* g = pb_g + (size_t)(/*n0 injected by caller via kc_ hack*/ 0);
            (void)g;
            s_ = s_;  // placate nothing
        }
    };
    (void)stage_pb;  // replaced below by explicit lambdas with captures

    // ---- x row norms: wave w does rows w*4..w*4+3; exchange via WT region ----
    {
        float* xn_s = (float*)WT;
        #pragma unroll
        for (int rr = 0; rr < 4; ++rr) {
            const int row = wave * 4 + rr;
            const float* xr = x + (size_t)(m0 + row) * D + lane * 8;
            const float4 a = *(const float4*)xr;
            const float4 b = *(const float4*)(xr + 4);
            float s = a.x*a.x + a.y*a.y + a.z*a.z + a.w*a.w
                    + b.x*b.x + b.y*b.y + b.z*b.z + b.w*b.w;
            #pragma unroll
            for (int off = 32; off > 0; off >>= 1) s += __shfl_down(s, off, 64);
            if (lane == 0) xn_s[row] = s;
        }
        __syncthreads();
    }
    const float xn_r = ((float*)WT)[wr * 16 + l15];
    __syncthreads();

    f32x4_t O[8];
    #pragma unroll
    for (int i = 0; i < 8; ++i) O[i] = (f32x4_t)0.f;
    float den_r = 0.f;

    for (int tile = 0; tile < NPOS / 256; ++tile) {
        const int n0 = tile * 256;

        auto STAGE_PB = [&](int kc_, int b_) {
            #pragma unroll
            for (int s_ = 0; s_ < 4; ++s_) {
                const int seg = wave * 4 + s_;
                const int nrel = seg * 8 + (lane >> 3);
                const u16* gp = pb_g + (size_t)(n0 + nrel) * D + kc_ * 64
                                + (lane & 7) * 8;
                async16(&PBbuf[b_][seg * 512], gp);
            }
        };
        auto STAGE_VT = [&](int c_, int b_) {
            #pragma unroll
            for (int s_ = 0; s_ < 4; ++s_) {
                const int seg = wave * 4 + s_;
                const int drel = seg * 8 + (lane >> 3);
                const u16* gp = vt_g + (size_t)((c_ & 1) * 256 + drel) * NPOS
                                + n0 + (c_ >> 1) * 64 + (lane & 7) * 8;
                async16(&PBbuf[b_][seg * 512], gp);
            }
        };

        // ================= GEMM1: S^T[256][32] =================
        f32x4_t S[4];
        #pragma unroll
        for (int j = 0; j < 4; ++j) S[j] = (f32x4_t)0.f;

        STAGE_PB(0, 0);
        __syncthreads();
        int buf = 0;
        for (int kc = 0; kc < 8; ++kc) {
            if (kc < 7) STAGE_PB(kc + 1, buf ^ 1);
            #pragma unroll
            for (int ks = 0; ks < 2; ++ks) {
                // A-frags: p rows n = wc*64 + j*16 + l15
                short8_t A0, A1, A2, A3;
                {
                    const int slot = ((ks * 4 + q) ^ swz) * 8;
                    const u16* base = &PBbuf[buf][(wc * 64 + l15) * 64 + slot];
                    A0 = *(const short8_t*)(base + 0 * 1024);
                    A1 = *(const short8_t*)(base + 1 * 1024);
                    A2 = *(const short8_t*)(base + 2 * 1024);
                    A3 = *(const short8_t*)(base + 3 * 1024);
                }
                // B-frag: x row m = wr*16+l15, k = kc*64+ks*32+q*8, hi/lo in regs
                short8_t bh, bl;
                {
                    const float* xp = x + (size_t)(m0 + wr * 16 + l15) * D
                                      + kc * 64 + ks * 32 + q * 8;
                    const float4 f0 = *(const float4*)xp;
                    const float4 f1 = *(const float4*)(xp + 4);
                    const float f[8] = {f0.x, f0.y, f0.z, f0.w, f1.x, f1.y, f1.z, f1.w};
                    #pragma unroll
                    for (int c = 0; c < 8; ++c) {
                        const u16 h = f2bf(f[c]);
                        ((u16*)&bh)[c] = h;
                        ((u16*)&bl)[c] = f2bf(f[c] - bf2f(h));
                    }
                }
                S[0] = __builtin_amdgcn_mfma_f32_16x16x32_bf16(A0, bh, S[0], 0, 0, 0);
                S[0] = __builtin_amdgcn_mfma_f32_16x16x32_bf16(A0, bl, S[0], 0, 0, 0);
                S[1] = __builtin_amdgcn_mfma_f32_16x16x32_bf16(A1, bh, S[1], 0, 0, 0);
                S[1] = __builtin_amdgcn_mfma_f32_16x16x32_bf16(A1, bl, S[1], 0, 0, 0);
                S[2] = __builtin_amdgcn_mfma_f32_16x16x32_bf16(A2, bh, S[2], 0, 0, 0);
                S[2] = __builtin_amdgcn_mfma_f32_16x16x32_bf16(A2, bl, S[2], 0, 0, 0);
                S[3] = __builtin_amdgcn_mfma_f32_16x16x32_bf16(A3, bh, S[3], 0, 0, 0);
                S[3] = __builtin_amdgcn_mfma_f32_16x16x32_bf16(A3, bl, S[3], 0, 0, 0);
            }
            __syncthreads();
            buf ^= 1;
        }

        // ====== epilogue: w -> WT (bf16, swizzled b32 writes), den in regs ======
        #pragma unroll
        for (int j = 0; j < 4; ++j) {
            const int nb = n0 + wc * 64 + j * 16 + q * 4;
            const float4 pn = *(const float4*)(pn_arr + nb);
            const float4 it = *(const float4*)(it_arr + nb);
            u16 h[4];
            {
                const float pnv[4] = {pn.x, pn.y, pn.z, pn.w};
                const float itv[4] = {it.x, it.y, it.z, it.w};
                #pragma unroll
                for (int r = 0; r < 4; ++r) {
                    const float d2 = xn_r + pnv[r] - 2.f * S[j][r];
                    const float w  = __expf(sqrtf(fmaxf(d2, 0.f)) * itv[r]);
                    h[r] = f2bf(w);
                    den_r += bf2f(h[r]);
                }
            }
            const unsigned w01 = (unsigned)h[0] | ((unsigned)h[1] << 16);
            const unsigned w23 = (unsigned)h[2] | ((unsigned)h[3] << 16);
            const int base = (wr * 16 + l15) * 256 + wc * 64
                           + (((j * 2 + (q >> 1)) ^ swz) * 8) + (q & 1) * 4;
            *(unsigned*)&WT[base]     = w01;
            *(unsigned*)&WT[base + 2] = w23;
        }

        STAGE_VT(0, 0);
        __syncthreads();

        // ================= GEMM2: O += WT @ V =================
        int vbuf = 0;
        short8_t Aw0, Aw1;
        for (int c = 0; c < 8; ++c) {
            const int nc = c >> 1, dh = c & 1;
            if (c < 7) STAGE_VT(c + 1, vbuf ^ 1);
            if (dh == 0) {
                const u16* base = &WT[(wr * 16 + l15) * 256 + nc * 64];
                Aw0 = *(const short8_t*)(base + (((0 * 4 + q) ^ swz) * 8));
                Aw1 = *(const short8_t*)(base + (((1 * 4 + q) ^ swz) * 8));
            }
            #pragma unroll
            for (int ks = 0; ks < 2; ++ks) {
                const short8_t Aw = ks ? Aw1 : Aw0;
                const int slot = ((ks * 4 + q) ^ swz) * 8;
                const u16* base = &PBbuf[vbuf][(wc * 64 + l15) * 64 + slot];
                #pragma unroll
                for (int j4 = 0; j4 < 4; ++j4) {
                    const short8_t B = *(const short8_t*)(base + j4 * 1024);
                    O[dh * 4 + j4] =
                        __builtin_amdgcn_mfma_f32_16x16x32_bf16(Aw, B, O[dh * 4 + j4], 0, 0, 0);
                }
            }
            __syncthreads();
            vbuf ^= 1;
        }
    }

    // ================= den reduce + normalize + store =================
    {
        float s = den_r;
        s += __shfl_xor(s, 16, 64);
        s += __shfl_xor(s, 32, 64);
        float* den_s = (float*)WT;  // WT free after last GEMM2 barrier
        if (lane < 16) den_s[wave * 16 + lane] = s;
        __syncthreads();
        float inv[4];
        #pragma unroll
        for (int r = 0; r < 4; ++r) {
            const int slot = q * 4 + r;
            const float dd = den_s[(wr + 0) * 16 + slot] + den_s[(wr + 2) * 16 + slot]
                           + den_s[(wr + 4) * 16 + slot] + den_s[(wr + 6) * 16 + slot];
            inv[r] = 1.f / (dd + 1e-8f);
        }
        #pragma unroll
        for (int dh = 0; dh < 2; ++dh)
            #pragma unroll
            for (int j4 = 0; j4 < 4; ++j4) {
                const int d = dh * 256 + wc * 64 + j4 * 16 + l15;
                #pragma unroll
                for (int r = 0; r < 4; ++r) {
                    const int m = wr * 16 + q * 4 + r;
                    out[(size_t)(m0 + m) * D + d] = O[dh * 4 + j4][r] * inv[r];
                }
            }
    }
}

extern "C" void kernel_launch(void* const* d_in, const int* in_sizes, int n_in,
                              void* d_out, int out_size, void* d_ws, size_t ws_size,
                              hipStream_t stream) {
    const float* xp  = (const float*)d_in[0];
    const float* pos = (const float*)d_in[1];
    const float* val = (const float*)d_in[2];
    const float* tmp = (const float*)d_in[3];
    const float* fsc = (const float*)d_in[4];
    const int*   frz = (const int*)d_in[5];
    float* outp = (float*)d_out;

    float* ws   = (float*)d_ws;
    u16*   pb_g = (u16*)((char*)d_ws + 32768);
    u16*   vt_g = (u16*)((char*)d_ws + 32768 + (size_t)NPOS * D * 2);

    pn_kernel<<<NPOS / 4, 256, 0, stream>>>(pos, tmp, fsc, frz, ws);
    pb_pre<<<NPOS * 64 / 256, 256, 0, stream>>>(pos, pb_g);
    vt_pre<<<dim3(NPOS / 64, D / 64), 256, 0, stream>>>(val, vt_g);
    tidal_mfma<<<M / 32, 512, 0, stream>>>(xp, ws, pb_g, vt_g, outp);
}

// Round 6
// 327.299 us; speedup vs baseline: 7.4332x; 1.8669x over previous
//
#include <hip/hip_runtime.h>
#include <math.h>

// B=8,T=2048,D=512,N=4096
static constexpr int D    = 512;
static constexpr int NPOS = 4096;
static constexpr int M    = 16384;
static constexpr float MIN_SCALE = 0.05f;

typedef unsigned short u16;
typedef __attribute__((ext_vector_type(8)))  short short8_t;   // bf16x8 MFMA frag (4 VGPR)
typedef __attribute__((ext_vector_type(16))) float f32x16_t;   // 32x32 MFMA acc
typedef __attribute__((ext_vector_type(8)))  unsigned short ushort8_t;

__device__ __forceinline__ u16 f2bf(float f) {
    unsigned u = __float_as_uint(f);
    unsigned r = (u + 0x7FFFu + ((u >> 16) & 1u)) >> 16;  // RN-even
    return (u16)r;
}
__device__ __forceinline__ float bf2f(u16 h) {
    return __uint_as_float(((unsigned)h) << 16);
}
__device__ __forceinline__ void async16(void* lds, const void* gp) {
    __builtin_amdgcn_global_load_lds(
        (const __attribute__((address_space(1))) unsigned int*)gp,
        (__attribute__((address_space(3))) unsigned int*)lds, 16, 0, 0);
}

// ---------------------------------------------------------------------------
// ws layout (floats unless noted):
//   [0)      pn   f32[4096]
//   [4096)   nit  f32[4096]       -1/((|t|+0.1)*scale)
//   [8192)   xn   f32[16384]
//   byte 98304:   PB3 u16, frag-packed: idx ((ng*32+kg)*64+lane)*8
//                   n = ng*32+(lane&31), k = kg*16+(lane>>5)*8+c     (4 MB)
//   byte 4292608: VT3 u16, frag-packed: idx ((dg*256+kg)*64+lane)*8
//                   d = dg*32+(lane&31), n = kg*16+(lane>>5)*8+c     (4 MB)
//   byte 8486912: XB3 u16, frag-packed: idx ((mg*32+kg)*64+lane)*8
//                   m = mg*32+(lane&31), k = kg*16+(lane>>5)*8+c     (16 MB)
// ---------------------------------------------------------------------------

// Fused precompute: one launch, roles by blockIdx.x (256 threads each).
//   [0,1024)      pn/nit        [1024,5120) xn
//   [5120,9216)   XB3 pack      [9216,10240) PB3 pack
//   [10240,10752) VT3 pack (LDS transpose)
__global__ __launch_bounds__(256) void pre_kernel(
    const float* __restrict__ x, const float* __restrict__ pos,
    const float* __restrict__ val, const float* __restrict__ temperature,
    const float* __restrict__ frozen_scale, const int* __restrict__ frozen,
    float* __restrict__ ws_f, u16* __restrict__ pb3, u16* __restrict__ vt3,
    u16* __restrict__ xb3)
{
    const int b   = blockIdx.x;
    const int tid = threadIdx.x;

    if (b < 1024) {  // pn / nit
        const int wv = tid >> 6, lane = tid & 63;
        const int n  = b * 4 + wv;
        const float* row = pos + (size_t)n * D;
        float s = 0.f;
        #pragma unroll
        for (int q = 0; q < D; q += 64) { float v = row[q + lane]; s += v * v; }
        #pragma unroll
        for (int off = 32; off > 0; off >>= 1) s += __shfl_down(s, off, 64);
        if (lane == 0) {
            ws_f[n] = s;
            float es = (frozen[n] != 0) ? frozen_scale[n] : MIN_SCALE;
            float et = (fabsf(temperature[n]) + 0.1f) * es;
            ws_f[NPOS + n] = -1.0f / et;
        }
    } else if (b < 5120) {  // xn
        const int wv = tid >> 6, lane = tid & 63;
        const int m  = (b - 1024) * 4 + wv;
        const float* row = x + (size_t)m * D;
        float s = 0.f;
        #pragma unroll
        for (int q = 0; q < D; q += 64) { float v = row[q + lane]; s += v * v; }
        #pragma unroll
        for (int off = 32; off > 0; off >>= 1) s += __shfl_down(s, off, 64);
        if (lane == 0) ws_f[2 * NPOS + m] = s;
    } else if (b < 9216) {  // XB3 pack (frag index f is linear!)
        const size_t f = (size_t)(b - 5120) * 256 + tid;
        const int lane = (int)(f & 63);
        const int kg   = (int)((f >> 6) & 31);
        const int mg   = (int)(f >> 11);
        const float* src = x + ((size_t)(mg * 32 + (lane & 31)) * D
                                + kg * 16 + (lane >> 5) * 8);
        const float4 a = *(const float4*)src;
        const float4 c = *(const float4*)(src + 4);
        ushort8_t v;
        v[0]=f2bf(a.x); v[1]=f2bf(a.y); v[2]=f2bf(a.z); v[3]=f2bf(a.w);
        v[4]=f2bf(c.x); v[5]=f2bf(c.y); v[6]=f2bf(c.z); v[7]=f2bf(c.w);
        *(ushort8_t*)(xb3 + f * 8) = v;
    } else if (b < 10240) {  // PB3 pack
        const size_t f = (size_t)(b - 9216) * 256 + tid;
        const int lane = (int)(f & 63);
        const int kg   = (int)((f >> 6) & 31);
        const int ng   = (int)(f >> 11);
        const float* src = pos + ((size_t)(ng * 32 + (lane & 31)) * D
                                  + kg * 16 + (lane >> 5) * 8);
        const float4 a = *(const float4*)src;
        const float4 c = *(const float4*)(src + 4);
        ushort8_t v;
        v[0]=f2bf(a.x); v[1]=f2bf(a.y); v[2]=f2bf(a.z); v[3]=f2bf(a.w);
        v[4]=f2bf(c.x); v[5]=f2bf(c.y); v[6]=f2bf(c.z); v[7]=f2bf(c.w);
        *(ushort8_t*)(pb3 + f * 8) = v;
    } else {  // VT3 pack: 64n x 64d tile transpose via LDS
        __shared__ __attribute__((aligned(16))) float tile[64 * 68];
        const int b2 = b - 10240;
        const int n0 = (b2 & 63) * 64, d0 = (b2 >> 6) * 64;
        {
            const int row = tid >> 2, c0 = (tid & 3) * 16;
            const float* src = val + (size_t)(n0 + row) * D + d0 + c0;
            #pragma unroll
            for (int i = 0; i < 4; ++i)
                *(float4*)&tile[row * 68 + c0 + i * 4] = *(const float4*)(src + i * 4);
        }
        __syncthreads();
        #pragma unroll
        for (int ff = 0; ff < 2; ++ff) {
            const int f    = ff * 256 + tid;
            const int lane = f & 63;
            const int kgl  = (f >> 6) & 3;
            const int dgl  = (f >> 8) & 1;
            const int d_loc = dgl * 32 + (lane & 31);
            const int n_base = kgl * 16 + (lane >> 5) * 8;
            ushort8_t v;
            #pragma unroll
            for (int c = 0; c < 8; ++c) v[c] = f2bf(tile[(n_base + c) * 68 + d_loc]);
            const int dg = (d0 >> 5) + dgl;
            const int kga = (n0 >> 4) + kgl;
            *(ushort8_t*)(vt3 + ((size_t)(dg * 256 + kga) * 64 + lane) * 8) = v;
        }
    }
}

// ---------------------------------------------------------------------------
// Main kernel: 256 blocks x 1024 threads (16 waves), m-tile 64, n-tile 256.
// All operands frag-packed -> barrier-free K-loops, mfma_32x32x16_bf16.
// Wave roles: mh = wave&1 (m half), wq = wave>>1 (ng in GEMM1 / dq in GEMM2).
// ---------------------------------------------------------------------------
__global__ __launch_bounds__(1024, 4) void tidal_main(
    const float* __restrict__ ws_f, const u16* __restrict__ pb3,
    const u16* __restrict__ vt3, const u16* __restrict__ xb3,
    float* __restrict__ out)
{
    __shared__ __attribute__((aligned(16))) u16 XBL[2][32][512];  // 64KB x-frags
    __shared__ __attribute__((aligned(16))) u16 WTF[2][16][512];  // 32KB w-frags
    __shared__ float red[2][8][32];                               // den partials
    __shared__ float inv_s[64];

    const float* pn_arr = ws_f;
    const float* it_arr = ws_f + NPOS;
    const float* xn_arr = ws_f + 2 * NPOS;

    const int tid  = threadIdx.x;
    const int lane = tid & 63;
    const int wave = tid >> 6;        // 0..15
    const int h    = lane >> 5;       // k-half within frag
    const int l31  = lane & 31;
    const int mh   = wave & 1;
    const int wq   = wave >> 1;       // 0..7
    const int m0   = blockIdx.x * 64;

    // stage this block's x-frags (2 mg x 32 kg x 1KB) once, reused all tiles
    {
        const u16* xb_blk = xb3 + (size_t)blockIdx.x * (2 * 32 * 512);
        #pragma unroll
        for (int s = 0; s < 4; ++s) {
            const int seg = wave * 4 + s;
            async16(&XBL[0][0][0] + seg * 512, xb_blk + (size_t)seg * 512 + lane * 8);
        }
    }
    __syncthreads();

    const float xn_r = xn_arr[m0 + mh * 32 + l31];

    f32x16_t O0 = (f32x16_t)0.f, O1 = (f32x16_t)0.f;
    float den_r = 0.f;

    for (int tile = 0; tile < NPOS / 256; ++tile) {
        const int n0 = tile * 256;

        // ---------- GEMM1: S (32n x 32m per wave), no barriers ----------
        f32x16_t S = (f32x16_t)0.f;
        const u16* pbw = pb3 + (size_t)(tile * 8 + wq) * 32 * 512;
        #pragma unroll 4
        for (int kg = 0; kg < 32; ++kg) {
            const short8_t A = *(const short8_t*)(pbw + (size_t)kg * 512 + lane * 8);
            const short8_t B = *(const short8_t*)&XBL[mh][kg][lane * 8];
            S = __builtin_amdgcn_mfma_f32_32x32x16_bf16(A, B, S, 0, 0, 0);
        }

        // ---------- epilogue: w = exp(-d/t) -> WTF (frag-packed) ----------
        #pragma unroll
        for (int t = 0; t < 4; ++t) {
            const int nb = n0 + wq * 32 + 8 * t + 4 * h;
            const float4 pn4 = *(const float4*)(pn_arr + nb);
            const float4 it4 = *(const float4*)(it_arr + nb);
            const float pnv[4] = {pn4.x, pn4.y, pn4.z, pn4.w};
            const float itv[4] = {it4.x, it4.y, it4.z, it4.w};
            u16 hh[4];
            #pragma unroll
            for (int r = 0; r < 4; ++r) {
                const float d2 = xn_r + pnv[r] - 2.f * S[4 * t + r];
                const float w  = __expf(sqrtf(fmaxf(d2, 0.f)) * itv[r]);
                hh[r] = f2bf(w);
                den_r += bf2f(hh[r]);   // den consistent with bf16 numerator
            }
            // target frag: kg = wq*2+(t>>1), lane' = l31 + 32*(t&1), c = 4h+r
            u16* dst = &WTF[mh][wq * 2 + (t >> 1)][(l31 + 32 * (t & 1)) * 8 + 4 * h];
            *(unsigned*)(dst)     = (unsigned)hh[0] | ((unsigned)hh[1] << 16);
            *(unsigned*)(dst + 2) = (unsigned)hh[2] | ((unsigned)hh[3] << 16);
        }
        __syncthreads();

        // ---------- GEMM2: O += W @ V (32m x 64d per wave), no barriers ----------
        #pragma unroll 4
        for (int nkg = 0; nkg < 16; ++nkg) {
            const int kga = tile * 16 + nkg;
            const short8_t A  = *(const short8_t*)&WTF[mh][nkg][lane * 8];
            const short8_t B0 = *(const short8_t*)(vt3 + ((size_t)(wq * 256 + kga) * 64 + lane) * 8);
            const short8_t B1 = *(const short8_t*)(vt3 + ((size_t)((wq + 8) * 256 + kga) * 64 + lane) * 8);
            O0 = __builtin_amdgcn_mfma_f32_32x32x16_bf16(A, B0, O0, 0, 0, 0);
            O1 = __builtin_amdgcn_mfma_f32_32x32x16_bf16(A, B1, O1, 0, 0, 0);
        }
        __syncthreads();   // WAR: next tile rewrites WTF
    }

    // ---------- den reduce + normalize + store ----------
    den_r += __shfl_xor(den_r, 32, 64);
    if (lane < 32) red[mh][wq][l31] = den_r;
    __syncthreads();
    if (tid < 64) {
        float s = 0.f;
        #pragma unroll
        for (int j = 0; j < 8; ++j) s += red[tid >> 5][j][tid & 31];
        inv_s[tid] = 1.f / (s + 1e-8f);
    }
    __syncthreads();

    #pragma unroll
    for (int t = 0; t < 4; ++t) {
        #pragma unroll
        for (int r = 0; r < 4; ++r) {
            const int mr = 8 * t + 4 * h + r;              // row within 32
            const float iv = inv_s[mh * 32 + mr];
            float* orow = out + (size_t)(m0 + mh * 32 + mr) * D;
            orow[wq * 32 + l31]       = O0[4 * t + r] * iv;
            orow[256 + wq * 32 + l31] = O1[4 * t + r] * iv;
        }
    }
}

extern "C" void kernel_launch(void* const* d_in, const int* in_sizes, int n_in,
                              void* d_out, int out_size, void* d_ws, size_t ws_size,
                              hipStream_t stream) {
    const float* xp  = (const float*)d_in[0];
    const float* pos = (const float*)d_in[1];
    const float* val = (const float*)d_in[2];
    const float* tmp = (const float*)d_in[3];
    const float* fsc = (const float*)d_in[4];
    const int*   frz = (const int*)d_in[5];
    float* outp = (float*)d_out;

    float* ws_f = (float*)d_ws;
    u16*   pb3  = (u16*)((char*)d_ws + 98304);
    u16*   vt3  = (u16*)((char*)d_ws + 4292608);
    u16*   xb3  = (u16*)((char*)d_ws + 8486912);

    pre_kernel<<<10752, 256, 0, stream>>>(xp, pos, val, tmp, fsc, frz,
                                          ws_f, pb3, vt3, xb3);
    tidal_main<<<M / 64, 1024, 0, stream>>>(ws_f, pb3, vt3, xb3, outp);
}